// Round 8
// baseline (108.672 us; speedup 1.0000x reference)
//
#include <hip/hip_runtime.h>

namespace {

constexpr int Tt = 32;    // frames (t)
constexpr int Ss = 784;   // floats per row (h*w)

using bf16x8 = __attribute__((ext_vector_type(8))) short;
using f32x4  = __attribute__((ext_vector_type(4))) float;

// split fp32 -> hi (truncated bf16) + lo (bf16 of residual); pack 2 per uint
__device__ inline void cvt2(float a, float b, unsigned& h, unsigned& l) {
  const unsigned ha = __float_as_uint(a) >> 16;
  const unsigned hb = __float_as_uint(b) >> 16;
  const float ra = a - __uint_as_float(ha << 16);
  const float rb = b - __uint_as_float(hb << 16);
  const unsigned la = __float_as_uint(ra) >> 16;
  const unsigned lb = __float_as_uint(rb) >> 16;
  h = ha | (hb << 16);
  l = la | (lb << 16);
}

// ---------------------------------------------------------------------------
// Kernel 1: per-(b,c) Gram via split-bf16 MFMA (unchanged from round 7,
// measured ~29 us). C = HI*HI^T + HI*LO^T + LO*HI^T.
// ---------------------------------------------------------------------------
__global__ __launch_bounds__(256, 3) void gram_partial(const float* __restrict__ x,
                                                       float* __restrict__ part) {
  const int bc = blockIdx.x;                       // b*64 + c
  const float* __restrict__ xb = x + (size_t)bc * (Tt * Ss);
  const int tid  = threadIdx.x;
  const int w    = tid >> 6;          // wave 0..3
  const int lane = tid & 63;

  __shared__ uint4 HI[13 * 128];      // 26624 B
  __shared__ uint4 LO[13 * 128];      // 26624 B

  f32x4 d1[2][2], d2[2][2], d3[2][2];
#pragma unroll
  for (int i = 0; i < 2; ++i)
#pragma unroll
    for (int j = 0; j < 2; ++j) { d1[i][j] = 0.f; d2[i][j] = 0.f; d3[i][j] = 0.f; }

  const int fbase = ((lane >> 4) << 5) + (lane & 15);   // frag chunk idx within kstep

#pragma unroll
  for (int phase = 0; phase < 2; ++phase) {
    const int sb  = phase ? 416 : 0;
    const int nks = phase ? 12 : 13;

    // ---- stage: fp32 -> hi/lo bf16, fragment-ordered chunks of 8 ----
    for (int f = tid; f < nks * 128; f += 256) {
      const int ks  = f >> 7;
      const int idx = f & 127;
      const int kg  = idx >> 5;
      const int row = idx & 31;
      const int s   = sb + ks * 32 + kg * 8;
      uint4 h = {0u, 0u, 0u, 0u}, l = {0u, 0u, 0u, 0u};
      if (s < 784) {
        const float* p = xb + row * Ss + s;
        const float4 v0 = *reinterpret_cast<const float4*>(p);
        const float4 v1 = *reinterpret_cast<const float4*>(p + 4);
        cvt2(v0.x, v0.y, h.x, l.x);
        cvt2(v0.z, v0.w, h.y, l.y);
        cvt2(v1.x, v1.y, h.z, l.z);
        cvt2(v1.z, v1.w, h.w, l.w);
      }
      HI[f] = h;
      LO[f] = l;
    }
    __syncthreads();

    // ---- MFMA: wave w owns ksteps ks % 4 == w ----
    for (int ks = w; ks < nks; ks += 4) {
      const int base = ks * 128 + fbase;
      const uint4 h0u = HI[base], h1u = HI[base + 16];
      const uint4 l0u = LO[base], l1u = LO[base + 16];
      const bf16x8 h0 = __builtin_bit_cast(bf16x8, h0u);
      const bf16x8 h1 = __builtin_bit_cast(bf16x8, h1u);
      const bf16x8 l0 = __builtin_bit_cast(bf16x8, l0u);
      const bf16x8 l1 = __builtin_bit_cast(bf16x8, l1u);
      d1[0][0] = __builtin_amdgcn_mfma_f32_16x16x32_bf16(h0, h0, d1[0][0], 0, 0, 0);
      d1[0][1] = __builtin_amdgcn_mfma_f32_16x16x32_bf16(h0, h1, d1[0][1], 0, 0, 0);
      d1[1][0] = __builtin_amdgcn_mfma_f32_16x16x32_bf16(h1, h0, d1[1][0], 0, 0, 0);
      d1[1][1] = __builtin_amdgcn_mfma_f32_16x16x32_bf16(h1, h1, d1[1][1], 0, 0, 0);
      d2[0][0] = __builtin_amdgcn_mfma_f32_16x16x32_bf16(h0, l0, d2[0][0], 0, 0, 0);
      d2[0][1] = __builtin_amdgcn_mfma_f32_16x16x32_bf16(h0, l1, d2[0][1], 0, 0, 0);
      d2[1][0] = __builtin_amdgcn_mfma_f32_16x16x32_bf16(h1, l0, d2[1][0], 0, 0, 0);
      d2[1][1] = __builtin_amdgcn_mfma_f32_16x16x32_bf16(h1, l1, d2[1][1], 0, 0, 0);
      d3[0][0] = __builtin_amdgcn_mfma_f32_16x16x32_bf16(l0, h0, d3[0][0], 0, 0, 0);
      d3[0][1] = __builtin_amdgcn_mfma_f32_16x16x32_bf16(l0, h1, d3[0][1], 0, 0, 0);
      d3[1][0] = __builtin_amdgcn_mfma_f32_16x16x32_bf16(l1, h0, d3[1][0], 0, 0, 0);
      d3[1][1] = __builtin_amdgcn_mfma_f32_16x16x32_bf16(l1, h1, d3[1][1], 0, 0, 0);
    }
    __syncthreads();   // all frag reads done before restage / epilogue alias
  }

  // ---- epilogue: combine D1+D2+D3, reduce over 4 waves ----
  float* mtmp = reinterpret_cast<float*>(HI);   // [4][32*33] aliases HI
#pragma unroll
  for (int i = 0; i < 2; ++i)
#pragma unroll
    for (int j = 0; j < 2; ++j) {
      const f32x4 s4 = d1[i][j] + d2[i][j] + d3[i][j];
#pragma unroll
      for (int r = 0; r < 4; ++r) {
        const int row = i * 16 + ((lane >> 4) << 2) + r;   // m89-verified C/D map
        const int col = j * 16 + (lane & 15);
        mtmp[w * 1056 + row * 33 + col] = s4[r];
      }
    }
  __syncthreads();

  const int e0 = tid * 4;
  float tmp[4];
#pragma unroll
  for (int u = 0; u < 4; ++u) {
    const int row = (e0 + u) >> 5;
    const int col = (e0 + u) & 31;
    float ss = 0.f;
#pragma unroll
    for (int ww = 0; ww < 4; ++ww) ss += mtmp[ww * 1056 + row * 33 + col];
    tmp[u] = ss;
  }
  float4 o4;
  o4.x = tmp[0]; o4.y = tmp[1]; o4.z = tmp[2]; o4.w = tmp[3];
  *reinterpret_cast<float4*>(part + (size_t)bc * 1024 + e0) = o4;
}

// ---------------------------------------------------------------------------
// Kernel 2: reduce partials over c.  msum[b][e] = sum_c part[b*64+c][e]
// ---------------------------------------------------------------------------
__global__ __launch_bounds__(256) void reduce_c(const float* __restrict__ part,
                                                float* __restrict__ msum) {
  const int bid = blockIdx.x;                // 0..63
  const int b   = bid >> 2;
  const int e   = (bid & 3) * 256 + threadIdx.x;   // 0..1023
  const float* __restrict__ p = part + (size_t)b * 64 * 1024 + e;
  float s0 = 0.f, s1 = 0.f, s2 = 0.f, s3 = 0.f;
#pragma unroll
  for (int c = 0; c < 64; c += 4) {
    s0 += p[(size_t)(c + 0) * 1024];
    s1 += p[(size_t)(c + 1) * 1024];
    s2 += p[(size_t)(c + 2) * 1024];
    s3 += p[(size_t)(c + 3) * 1024];
  }
  msum[b * 1024 + e] = (s0 + s1) + (s2 + s3);
}

// ---------------------------------------------------------------------------
// Kernel 3: softmax over the BATCH axis + transpose to [k][q]-major.
// ---------------------------------------------------------------------------
__global__ __launch_bounds__(256) void softmax_b(const float* __restrict__ msum,
                                                 float* __restrict__ mt) {
  const int e = blockIdx.x * 256 + threadIdx.x;    // q*32 + k
  float l[16];
  float mx = -3.4e38f;
#pragma unroll
  for (int b = 0; b < 16; ++b) {
    l[b] = msum[b * 1024 + e];
    mx = fmaxf(mx, l[b]);
  }
  float s = 0.f;
#pragma unroll
  for (int b = 0; b < 16; ++b) {
    l[b] = expf(l[b] - mx);
    s += l[b];
  }
  const float inv = 1.f / s;
  const int et = (e & 31) * 32 + (e >> 5);         // k*32 + q
#pragma unroll
  for (int b = 0; b < 16; ++b) mt[b * 1024 + et] = l[b] * inv;
}

// ---------------------------------------------------------------------------
// Kernel 4: PV.  out[bc][q][s] = sum_k mt[b][k*32+q] * xv[bc][k][s]
// REWRITTEN: 1024 blocks x 512 threads (8 waves). Wave w: q-group w&3 (8 q
// rows), s-half w>>2 (392 floats). Lane owns 2 adjacent float4 cols (32 B
// contiguous per lane -> 1568 B fully-coalesced per wave-instr-pair).
// M coefficients via SAME-ADDRESS VECTOR float4 loads (all lanes load the
// identical L1-hot address -> 1-line broadcast, pipelined on vmcnt like any
// VMEM) — replaces round-7's scalar s_load chain that serialized the k-loop.
// ---------------------------------------------------------------------------
__global__ __launch_bounds__(512, 4) void pv(const float* __restrict__ xv,
                                             const float* __restrict__ mt,
                                             float* __restrict__ out) {
  const int bc = blockIdx.x;                  // b*64 + c
  const int b  = bc >> 6;
  const int tid  = threadIdx.x;
  const int w    = tid >> 6;                  // wave 0..7
  const int lane = tid & 63;
  const int q0    = 8 * (w & 3);              // q rows q0..q0+7
  const int sbase = 392 * (w >> 2);           // s-half

  const float* __restrict__ mp = mt + b * 1024 + q0;   // same addr across lanes

  if (lane < 49) {
    const float* __restrict__ src = xv + (size_t)bc * (Tt * Ss) + sbase + 8 * lane;
    float* __restrict__ dst       = out + (size_t)bc * (Tt * Ss) + sbase + 8 * lane;

    float4 acc[8][2] = {};

#pragma unroll 2
    for (int k = 0; k < 32; ++k) {
      const float4 v0 = *reinterpret_cast<const float4*>(src + (size_t)k * Ss);
      const float4 v1 = *reinterpret_cast<const float4*>(src + (size_t)k * Ss + 4);
      const float4 ma = *reinterpret_cast<const float4*>(mp + k * 32);      // q0..q0+3
      const float4 mb = *reinterpret_cast<const float4*>(mp + k * 32 + 4);  // q0+4..q0+7
      const float mm[8] = {ma.x, ma.y, ma.z, ma.w, mb.x, mb.y, mb.z, mb.w};
#pragma unroll
      for (int r = 0; r < 8; ++r) {
        const float m = mm[r];
        acc[r][0].x += m * v0.x; acc[r][0].y += m * v0.y;
        acc[r][0].z += m * v0.z; acc[r][0].w += m * v0.w;
        acc[r][1].x += m * v1.x; acc[r][1].y += m * v1.y;
        acc[r][1].z += m * v1.z; acc[r][1].w += m * v1.w;
      }
    }

#pragma unroll
    for (int r = 0; r < 8; ++r) {
      *reinterpret_cast<float4*>(dst + (size_t)(q0 + r) * Ss)     = acc[r][0];
      *reinterpret_cast<float4*>(dst + (size_t)(q0 + r) * Ss + 4) = acc[r][1];
    }
  }
}

}  // namespace

extern "C" void kernel_launch(void* const* d_in, const int* in_sizes, int n_in,
                              void* d_out, int out_size, void* d_ws, size_t ws_size,
                              hipStream_t stream) {
  const float* x  = (const float*)d_in[0];
  const float* xv = (const float*)d_in[1];
  float* out = (float*)d_out;

  // workspace (fp32), ~4.2 MiB total:
  float* part = (float*)d_ws;            // 1024 x 1024
  float* msum = part + 1024 * 1024;      // 16 x 1024
  float* mt   = msum + 16 * 1024;        // 16 x 1024 (k-major softmax weights)

  gram_partial<<<dim3(1024), dim3(256), 0, stream>>>(x, part);
  reduce_c<<<dim3(64), dim3(256), 0, stream>>>(part, msum);
  softmax_b<<<dim3(4), dim3(256), 0, stream>>>(msum, mt);
  pv<<<dim3(1024), dim3(512), 0, stream>>>(xv, mt, out);
}

// Round 9
// 87.452 us; speedup vs baseline: 1.2427x; 1.2427x over previous
//
#include <hip/hip_runtime.h>

namespace {

constexpr int Tt = 32;    // frames (t)
constexpr int Ss = 784;   // floats per row (h*w)

using bf16x8 = __attribute__((ext_vector_type(8))) short;
using f32x4  = __attribute__((ext_vector_type(4))) float;

// split fp32 -> hi (truncated bf16) + lo (bf16 of residual); pack 2 per uint
__device__ inline void cvt2(float a, float b, unsigned& h, unsigned& l) {
  const unsigned ha = __float_as_uint(a) >> 16;
  const unsigned hb = __float_as_uint(b) >> 16;
  const float ra = a - __uint_as_float(ha << 16);
  const float rb = b - __uint_as_float(hb << 16);
  const unsigned la = __float_as_uint(ra) >> 16;
  const unsigned lb = __float_as_uint(rb) >> 16;
  h = ha | (hb << 16);
  l = la | (lb << 16);
}

// ---------------------------------------------------------------------------
// Kernel 1: per-(b,c) Gram via split-bf16 MFMA (unchanged from round 7,
// measured ~29 us). C = HI*HI^T + HI*LO^T + LO*HI^T.
// ---------------------------------------------------------------------------
__global__ __launch_bounds__(256, 3) void gram_partial(const float* __restrict__ x,
                                                       float* __restrict__ part) {
  const int bc = blockIdx.x;                       // b*64 + c
  const float* __restrict__ xb = x + (size_t)bc * (Tt * Ss);
  const int tid  = threadIdx.x;
  const int w    = tid >> 6;          // wave 0..3
  const int lane = tid & 63;

  __shared__ uint4 HI[13 * 128];      // 26624 B
  __shared__ uint4 LO[13 * 128];      // 26624 B

  f32x4 d1[2][2], d2[2][2], d3[2][2];
#pragma unroll
  for (int i = 0; i < 2; ++i)
#pragma unroll
    for (int j = 0; j < 2; ++j) { d1[i][j] = 0.f; d2[i][j] = 0.f; d3[i][j] = 0.f; }

  const int fbase = ((lane >> 4) << 5) + (lane & 15);   // frag chunk idx within kstep

#pragma unroll
  for (int phase = 0; phase < 2; ++phase) {
    const int sb  = phase ? 416 : 0;
    const int nks = phase ? 12 : 13;

    // ---- stage: fp32 -> hi/lo bf16, fragment-ordered chunks of 8 ----
    for (int f = tid; f < nks * 128; f += 256) {
      const int ks  = f >> 7;
      const int idx = f & 127;
      const int kg  = idx >> 5;
      const int row = idx & 31;
      const int s   = sb + ks * 32 + kg * 8;
      uint4 h = {0u, 0u, 0u, 0u}, l = {0u, 0u, 0u, 0u};
      if (s < 784) {
        const float* p = xb + row * Ss + s;
        const float4 v0 = *reinterpret_cast<const float4*>(p);
        const float4 v1 = *reinterpret_cast<const float4*>(p + 4);
        cvt2(v0.x, v0.y, h.x, l.x);
        cvt2(v0.z, v0.w, h.y, l.y);
        cvt2(v1.x, v1.y, h.z, l.z);
        cvt2(v1.z, v1.w, h.w, l.w);
      }
      HI[f] = h;
      LO[f] = l;
    }
    __syncthreads();

    // ---- MFMA: wave w owns ksteps ks % 4 == w ----
    for (int ks = w; ks < nks; ks += 4) {
      const int base = ks * 128 + fbase;
      const uint4 h0u = HI[base], h1u = HI[base + 16];
      const uint4 l0u = LO[base], l1u = LO[base + 16];
      const bf16x8 h0 = __builtin_bit_cast(bf16x8, h0u);
      const bf16x8 h1 = __builtin_bit_cast(bf16x8, h1u);
      const bf16x8 l0 = __builtin_bit_cast(bf16x8, l0u);
      const bf16x8 l1 = __builtin_bit_cast(bf16x8, l1u);
      d1[0][0] = __builtin_amdgcn_mfma_f32_16x16x32_bf16(h0, h0, d1[0][0], 0, 0, 0);
      d1[0][1] = __builtin_amdgcn_mfma_f32_16x16x32_bf16(h0, h1, d1[0][1], 0, 0, 0);
      d1[1][0] = __builtin_amdgcn_mfma_f32_16x16x32_bf16(h1, h0, d1[1][0], 0, 0, 0);
      d1[1][1] = __builtin_amdgcn_mfma_f32_16x16x32_bf16(h1, h1, d1[1][1], 0, 0, 0);
      d2[0][0] = __builtin_amdgcn_mfma_f32_16x16x32_bf16(h0, l0, d2[0][0], 0, 0, 0);
      d2[0][1] = __builtin_amdgcn_mfma_f32_16x16x32_bf16(h0, l1, d2[0][1], 0, 0, 0);
      d2[1][0] = __builtin_amdgcn_mfma_f32_16x16x32_bf16(h1, l0, d2[1][0], 0, 0, 0);
      d2[1][1] = __builtin_amdgcn_mfma_f32_16x16x32_bf16(h1, l1, d2[1][1], 0, 0, 0);
      d3[0][0] = __builtin_amdgcn_mfma_f32_16x16x32_bf16(l0, h0, d3[0][0], 0, 0, 0);
      d3[0][1] = __builtin_amdgcn_mfma_f32_16x16x32_bf16(l0, h1, d3[0][1], 0, 0, 0);
      d3[1][0] = __builtin_amdgcn_mfma_f32_16x16x32_bf16(l1, h0, d3[1][0], 0, 0, 0);
      d3[1][1] = __builtin_amdgcn_mfma_f32_16x16x32_bf16(l1, h1, d3[1][1], 0, 0, 0);
    }
    __syncthreads();   // all frag reads done before restage / epilogue alias
  }

  // ---- epilogue: combine D1+D2+D3, reduce over 4 waves ----
  float* mtmp = reinterpret_cast<float*>(HI);   // [4][32*33] aliases HI
#pragma unroll
  for (int i = 0; i < 2; ++i)
#pragma unroll
    for (int j = 0; j < 2; ++j) {
      const f32x4 s4 = d1[i][j] + d2[i][j] + d3[i][j];
#pragma unroll
      for (int r = 0; r < 4; ++r) {
        const int row = i * 16 + ((lane >> 4) << 2) + r;   // m89-verified C/D map
        const int col = j * 16 + (lane & 15);
        mtmp[w * 1056 + row * 33 + col] = s4[r];
      }
    }
  __syncthreads();

  const int e0 = tid * 4;
  float tmp[4];
#pragma unroll
  for (int u = 0; u < 4; ++u) {
    const int row = (e0 + u) >> 5;
    const int col = (e0 + u) & 31;
    float ss = 0.f;
#pragma unroll
    for (int ww = 0; ww < 4; ++ww) ss += mtmp[ww * 1056 + row * 33 + col];
    tmp[u] = ss;
  }
  float4 o4;
  o4.x = tmp[0]; o4.y = tmp[1]; o4.z = tmp[2]; o4.w = tmp[3];
  *reinterpret_cast<float4*>(part + (size_t)bc * 1024 + e0) = o4;
}

// ---------------------------------------------------------------------------
// Kernel 2: reduce partials over c.  msum[b][e] = sum_c part[b*64+c][e]
// ---------------------------------------------------------------------------
__global__ __launch_bounds__(256) void reduce_c(const float* __restrict__ part,
                                                float* __restrict__ msum) {
  const int bid = blockIdx.x;                // 0..63
  const int b   = bid >> 2;
  const int e   = (bid & 3) * 256 + threadIdx.x;   // 0..1023
  const float* __restrict__ p = part + (size_t)b * 64 * 1024 + e;
  float s0 = 0.f, s1 = 0.f, s2 = 0.f, s3 = 0.f;
#pragma unroll
  for (int c = 0; c < 64; c += 4) {
    s0 += p[(size_t)(c + 0) * 1024];
    s1 += p[(size_t)(c + 1) * 1024];
    s2 += p[(size_t)(c + 2) * 1024];
    s3 += p[(size_t)(c + 3) * 1024];
  }
  msum[b * 1024 + e] = (s0 + s1) + (s2 + s3);
}

// ---------------------------------------------------------------------------
// Kernel 3: softmax over the BATCH axis. Output q-major: mq[b][q*32+k].
// ---------------------------------------------------------------------------
__global__ __launch_bounds__(256) void softmax_b(const float* __restrict__ msum,
                                                 float* __restrict__ mq) {
  const int e = blockIdx.x * 256 + threadIdx.x;    // q*32 + k
  float l[16];
  float mx = -3.4e38f;
#pragma unroll
  for (int b = 0; b < 16; ++b) {
    l[b] = msum[b * 1024 + e];
    mx = fmaxf(mx, l[b]);
  }
  float s = 0.f;
#pragma unroll
  for (int b = 0; b < 16; ++b) {
    l[b] = expf(l[b] - mx);
    s += l[b];
  }
  const float inv = 1.f / s;
#pragma unroll
  for (int b = 0; b < 16; ++b) mq[b * 1024 + e] = l[b] * inv;
}

// ---------------------------------------------------------------------------
// Kernel 4: PV via split-bf16 MFMA.  out[bc] = M[b] (32x32) * xv[bc] (32x784).
// 1024 blocks x 256 threads (4 waves), 4 blocks/CU (LDS 32.9 KB).
// K=32 = ONE 16x16x32 MFMA step -> no accumulator pressure (d is transient).
// out = Mh*Vh + Ml*Vh + Mh*Vl (lo*lo dropped, ~2^-16). M-frags built once per
// block from q-major mq (L2-hot). xv staged per 256-float s-chunk into LDS
// stride-257 fp32 (staging writes ~conflict-free via 8-row x 8-col lane remap;
// fragment reads exactly 2-way = free). Frag: lane reads 8 k-floats at its
// s-col, cvt -> Vh/Vl, 6 MFMA (2 q-frags x 3 terms), store D per m89 C/D map.
// ---------------------------------------------------------------------------
__global__ __launch_bounds__(256, 4) void pv(const float* __restrict__ xv,
                                             const float* __restrict__ mq,
                                             float* __restrict__ out) {
  const int bc = blockIdx.x;                  // b*64 + c
  const int b  = bc >> 6;
  const float* __restrict__ xvb = xv + (size_t)bc * (Tt * Ss);
  float* __restrict__ ob        = out + (size_t)bc * (Tt * Ss);

  const int tid  = threadIdx.x;
  const int w    = tid >> 6;                  // wave 0..3
  const int lane = tid & 63;
  const int col  = lane & 15;                 // frag column / M row
  const int g    = lane >> 4;                 // k-group (k = 8g..8g+7)

  __shared__ float lds[32 * 257];             // 32896 B

  // ---- M fragments (once per block) ----
  bf16x8 mh[2], ml[2];
#pragma unroll
  for (int qf = 0; qf < 2; ++qf) {
    const float* mp = mq + b * 1024 + (qf * 16 + col) * 32 + g * 8;
    const float4 ma = *reinterpret_cast<const float4*>(mp);
    const float4 mb = *reinterpret_cast<const float4*>(mp + 4);
    uint4 h, l;
    cvt2(ma.x, ma.y, h.x, l.x);
    cvt2(ma.z, ma.w, h.y, l.y);
    cvt2(mb.x, mb.y, h.z, l.z);
    cvt2(mb.z, mb.w, h.w, l.w);
    mh[qf] = __builtin_bit_cast(bf16x8, h);
    ml[qf] = __builtin_bit_cast(bf16x8, l);
  }

  for (int ch = 0; ch < 3; ++ch) {            // s-chunks of 256 floats
    // ---- stage 32 rows x 256 floats (coalesced 128B runs per 8 lanes) ----
#pragma unroll
    for (int it = 0; it < 8; ++it) {
      const int v   = it * 256 + tid;
      const int c8  = v & 7;
      const int row = (v >> 3) & 31;
      const int c4  = ((v >> 8) << 3) + c8;   // 0..63
      const float4 x4 = *reinterpret_cast<const float4*>(xvb + row * Ss + ch * 256 + c4 * 4);
      float* d = &lds[row * 257 + c4 * 4];
      d[0] = x4.x; d[1] = x4.y; d[2] = x4.z; d[3] = x4.w;
    }
    __syncthreads();

    // ---- compute: 16 frags, wave w owns sf = w, w+4, w+8, w+12 ----
#pragma unroll
    for (int sfi = 0; sfi < 4; ++sfi) {
      const int sf = w + sfi * 4;
      float f8[8];
#pragma unroll
      for (int j = 0; j < 8; ++j) f8[j] = lds[(g * 8 + j) * 257 + sf * 16 + col];
      uint4 hh, lv;
      cvt2(f8[0], f8[1], hh.x, lv.x);
      cvt2(f8[2], f8[3], hh.y, lv.y);
      cvt2(f8[4], f8[5], hh.z, lv.z);
      cvt2(f8[6], f8[7], hh.w, lv.w);
      const bf16x8 vh = __builtin_bit_cast(bf16x8, hh);
      const bf16x8 vl = __builtin_bit_cast(bf16x8, lv);
      const int s = ch * 256 + sf * 16 + col;
#pragma unroll
      for (int qf = 0; qf < 2; ++qf) {
        f32x4 d = {0.f, 0.f, 0.f, 0.f};
        d = __builtin_amdgcn_mfma_f32_16x16x32_bf16(mh[qf], vl, d, 0, 0, 0);
        d = __builtin_amdgcn_mfma_f32_16x16x32_bf16(ml[qf], vh, d, 0, 0, 0);
        d = __builtin_amdgcn_mfma_f32_16x16x32_bf16(mh[qf], vh, d, 0, 0, 0);
#pragma unroll
        for (int r = 0; r < 4; ++r)
          ob[(size_t)(qf * 16 + g * 4 + r) * Ss + s] = d[r];   // m89 C/D map
      }
    }
    __syncthreads();
  }

  // ---- tail frag: s 768..783, direct global reads (once, wave 0) ----
  if (w == 0) {
    float f8[8];
#pragma unroll
    for (int j = 0; j < 8; ++j) f8[j] = xvb[(size_t)(g * 8 + j) * Ss + 768 + col];
    uint4 hh, lv;
    cvt2(f8[0], f8[1], hh.x, lv.x);
    cvt2(f8[2], f8[3], hh.y, lv.y);
    cvt2(f8[4], f8[5], hh.z, lv.z);
    cvt2(f8[6], f8[7], hh.w, lv.w);
    const bf16x8 vh = __builtin_bit_cast(bf16x8, hh);
    const bf16x8 vl = __builtin_bit_cast(bf16x8, lv);
    const int s = 768 + col;
#pragma unroll
    for (int qf = 0; qf < 2; ++qf) {
      f32x4 d = {0.f, 0.f, 0.f, 0.f};
      d = __builtin_amdgcn_mfma_f32_16x16x32_bf16(mh[qf], vl, d, 0, 0, 0);
      d = __builtin_amdgcn_mfma_f32_16x16x32_bf16(ml[qf], vh, d, 0, 0, 0);
      d = __builtin_amdgcn_mfma_f32_16x16x32_bf16(mh[qf], vh, d, 0, 0, 0);
#pragma unroll
      for (int r = 0; r < 4; ++r)
        ob[(size_t)(qf * 16 + g * 4 + r) * Ss + s] = d[r];
    }
  }
}

}  // namespace

extern "C" void kernel_launch(void* const* d_in, const int* in_sizes, int n_in,
                              void* d_out, int out_size, void* d_ws, size_t ws_size,
                              hipStream_t stream) {
  const float* x  = (const float*)d_in[0];
  const float* xv = (const float*)d_in[1];
  float* out = (float*)d_out;

  // workspace (fp32), ~4.2 MiB total:
  float* part = (float*)d_ws;            // 1024 x 1024
  float* msum = part + 1024 * 1024;      // 16 x 1024
  float* mq   = msum + 16 * 1024;        // 16 x 1024 (q-major softmax weights)

  gram_partial<<<dim3(1024), dim3(256), 0, stream>>>(x, part);
  reduce_c<<<dim3(64), dim3(256), 0, stream>>>(part, msum);
  softmax_b<<<dim3(4), dim3(256), 0, stream>>>(msum, mq);
  pv<<<dim3(1024), dim3(256), 0, stream>>>(xv, mq, out);
}